// Round 9
// baseline (188.420 us; speedup 1.0000x reference)
//
#include <hip/hip_runtime.h>
#include <hip/hip_bf16.h>
#include <stdint.h>

// B=16, N=4096, H=512, K=2H=1024
//   pf[b,n,h]   = sum_k features[b,n,k] * Wf[h,k]
//   pq[b,h]     = sum_k query[b,k] * Wq[h,k]
//   logits[b,n] = 10*tanh( sum_h v[h]*tanh(pf+pq) )
// Outputs: pf (33554432 f32) then logits (65536 f32).
// R9: phase-interleaved schedule (T3+T4+T5 port). 128x512 tile, 8 waves
// (2m x 4n), BK=32, 32 K-tiles x 4 phases. Per phase: {ds_read subtile
// [+ stage slice]; barrier; cvt; setprio(1); 8 MFMA; setprio(0); barrier}.
// B staged to LDS as bf16 from fragment-ordered ws (4 gll, dbuf) -> no L1
// streaming in-loop; A fp32 via gll (2 gll, swizzled src, 3-buf, 2 ahead).
// Tile boundary = counted vmcnt(2) (A(t+1),B(t+1) landed; A(t+2) in flight),
// never a drain. Compiler owns lgkmcnt for ds_read->use deps.

#define KDIM 1024
#define HDIM 512

typedef short bf16x8 __attribute__((ext_vector_type(8)));
typedef float f32x4  __attribute__((ext_vector_type(4)));

__device__ __forceinline__ float fast_tanh(float x) {
    float ax = fabsf(x);
    float e  = __expf(-2.0f * ax);
    float r  = (1.0f - e) / (1.0f + e);
    return copysignf(r, x);
}

__device__ __forceinline__ short f2bf(float x) {
    __hip_bfloat16 b = __float2bfloat16(x);
    return (short)__builtin_bit_cast(unsigned short, b);
}

__device__ __forceinline__ bf16x8 cvt8(float4 a, float4 b) {
    bf16x8 o;
    o[0] = f2bf(a.x); o[1] = f2bf(a.y); o[2] = f2bf(a.z); o[3] = f2bf(a.w);
    o[4] = f2bf(b.x); o[5] = f2bf(b.y); o[6] = f2bf(b.z); o[7] = f2bf(b.w);
    return o;
}

// ---------------- Wf -> bf16 B-fragment order (proven R4-R8) ----------------
// chunk tid = (kt*32 + gg)*64 + lane, lane = fkg*16+fm:
// content = Wf[gg*16+fm][kt*32 + fkg*8 .. +8] as bf16x8.
__global__ void bshuf_kernel(const float* __restrict__ Wf, short* __restrict__ Bsh) {
    const int tid = blockIdx.x * 256 + threadIdx.x;   // 0..65535
    const int kt  = tid >> 11;
    const int gg  = (tid >> 6) & 31;
    const int ln  = tid & 63;
    const int fm  = ln & 15, fkg = ln >> 4;
    const int col = gg * 16 + fm;
    const int k0  = kt * 32 + fkg * 8;
    const float* src = Wf + col * KDIM + k0;
    float4 a = *(const float4*)src;
    float4 b = *(const float4*)(src + 4);
    *(bf16x8*)(Bsh + (size_t)tid * 8) = cvt8(a, b);
}

// ---------------- tiny GEMM: pq[b,h] ----------------
__global__ void pq_kernel(const float* __restrict__ query,
                          const float* __restrict__ Wq,
                          float* __restrict__ pq) {
    const int t = blockIdx.x * blockDim.x + threadIdx.x;   // 8192
    const int b = t >> 9, h = t & 511;
    const float4* q  = (const float4*)(query + (b << 9));
    const float4* wq = (const float4*)(Wq + ((size_t)h << 9));
    float s = 0.0f;
    #pragma unroll 4
    for (int i = 0; i < 128; ++i) {
        float4 a = q[i], c = wq[i];
        s += a.x * c.x + a.y * c.y + a.z * c.z + a.w * c.w;
    }
    pq[t] = s;
}

// ---------------- main GEMM + fused epilogue ----------------
// 512 blocks x 512 thr (8 waves, 2m x 4n). Tile 128x512, wave 64x128, BK=32.
__global__ __launch_bounds__(512) void gemm_kernel(
    const float* __restrict__ A, const short* __restrict__ Bsh,
    const float* __restrict__ pq, const float* __restrict__ v,
    float* __restrict__ pf, float* __restrict__ logits)
{
    __shared__ __align__(16) char ldsA[3][16384];   // A fp32 128x128B, 3-buf
    __shared__ __align__(16) char ldsB[2][32768];   // B bf16 frag-order, 2-buf
    __shared__ float uls[512];
    const int t    = threadIdx.x;
    const int lane = t & 63;
    const int w    = t >> 6;
    const int wm   = w >> 2;
    const int wn   = w & 3;
    const int fm   = lane & 15;
    const int fkg  = lane >> 4;
    const int Mbase = blockIdx.x * 128;

    // ---- A staging: chunk c=i*512+t; LDS(row,slot)=global(row,slot^(row&7))
    int asrc[2];
    #pragma unroll
    for (int i = 0; i < 2; ++i) {
        const int c = i * 512 + t;
        const int row = c >> 3, slot = c & 7;
        asrc[i] = row * 4096 + ((slot ^ (row & 7)) << 4);
    }
    const char* Ab = (const char*)(A + (size_t)Mbase * KDIM);
    const char* Bsrc = (const char*)Bsh;

    // ---- A fragment ds_read offsets (swizzled) ----
    int ard[4][2];
    #pragma unroll
    for (int f = 0; f < 4; ++f) {
        const int r = wm * 64 + f * 16 + fm;
        ard[f][0] = r * 128 + (((fkg * 2    ) ^ (r & 7)) << 4);
        ard[f][1] = r * 128 + (((fkg * 2 + 1) ^ (r & 7)) << 4);
    }
    const int brd = wn * 8192 + lane * 16;   // B frag base within ldsB buf

    f32x4 acc[4][8];
    const f32x4 zf = {0.0f, 0.0f, 0.0f, 0.0f};
    #pragma unroll
    for (int f = 0; f < 4; ++f)
        #pragma unroll
        for (int g = 0; g < 8; ++g) acc[f][g] = zf;

    #define STAGE_A(BUF, KT) do {                                            \
        _Pragma("unroll")                                                    \
        for (int i = 0; i < 2; ++i)                                          \
            __builtin_amdgcn_global_load_lds(                                \
                (const __attribute__((address_space(1))) void*)              \
                    (Ab + asrc[i] + ((KT) & 31) * 128),                      \
                (__attribute__((address_space(3))) void*)                    \
                    (&ldsA[BUF][(i * 512 + t) * 16]), 16, 0, 0);             \
    } while (0)

    #define STAGE_B(BUF, KT) do {                                            \
        const char* bs_ = Bsrc + (size_t)((KT) & 31) * 32768;                \
        _Pragma("unroll")                                                    \
        for (int i = 0; i < 4; ++i)                                          \
            __builtin_amdgcn_global_load_lds(                                \
                (const __attribute__((address_space(1))) void*)              \
                    (bs_ + (i * 512 + t) * 16),                              \
                (__attribute__((address_space(3))) void*)                    \
                    (&ldsB[BUF][(i * 512 + t) * 16]), 16, 0, 0);             \
    } while (0)

    #define BARRIER do { asm volatile("" ::: "memory");                      \
        __builtin_amdgcn_s_barrier();                                        \
        asm volatile("" ::: "memory"); } while (0)

    // ---- prologue: A(0), B(0), A(1) in flight; wait A(0),B(0) ----
    STAGE_A(0, 0);
    STAGE_B(0, 0);
    STAGE_A(1, 1);
    asm volatile("s_waitcnt vmcnt(2)" ::: "memory");
    BARRIER;

    bf16x8 bfr[8], abf;
    float4 ra0, ra1;

    #pragma unroll 1
    for (int kt = 0; kt < 32; ++kt) {
        const char* aB = ldsA[kt % 3];
        const char* bB = ldsB[kt & 1];

        // ---- phase 0: B frags + A(f=0) reads; MFMA f=0 ----
        #pragma unroll
        for (int g = 0; g < 8; ++g)
            bfr[g] = *(const bf16x8*)(bB + brd + g * 1024);
        ra0 = *(const float4*)(aB + ard[0][0]);
        ra1 = *(const float4*)(aB + ard[0][1]);
        BARRIER;
        abf = cvt8(ra0, ra1);
        __builtin_amdgcn_s_setprio(1);
        #pragma unroll
        for (int g = 0; g < 8; ++g)
            acc[0][g] = __builtin_amdgcn_mfma_f32_16x16x32_bf16(
                abf, bfr[g], acc[0][g], 0, 0, 0);
        __builtin_amdgcn_s_setprio(0);
        BARRIER;

        // ---- phase 1: A(f=1) read + stage B(kt+1); MFMA f=1 ----
        ra0 = *(const float4*)(aB + ard[1][0]);
        ra1 = *(const float4*)(aB + ard[1][1]);
        STAGE_B((kt + 1) & 1, kt + 1);
        BARRIER;
        abf = cvt8(ra0, ra1);
        __builtin_amdgcn_s_setprio(1);
        #pragma unroll
        for (int g = 0; g < 8; ++g)
            acc[1][g] = __builtin_amdgcn_mfma_f32_16x16x32_bf16(
                abf, bfr[g], acc[1][g], 0, 0, 0);
        __builtin_amdgcn_s_setprio(0);
        BARRIER;

        // ---- phase 2: A(f=2) read + stage A(kt+2); MFMA f=2 ----
        ra0 = *(const float4*)(aB + ard[2][0]);
        ra1 = *(const float4*)(aB + ard[2][1]);
        STAGE_A((kt + 2) % 3, kt + 2);
        BARRIER;
        abf = cvt8(ra0, ra1);
        __builtin_amdgcn_s_setprio(1);
        #pragma unroll
        for (int g = 0; g < 8; ++g)
            acc[2][g] = __builtin_amdgcn_mfma_f32_16x16x32_bf16(
                abf, bfr[g], acc[2][g], 0, 0, 0);
        __builtin_amdgcn_s_setprio(0);
        BARRIER;

        // ---- phase 3: A(f=3) read; MFMA f=3; counted boundary wait ----
        ra0 = *(const float4*)(aB + ard[3][0]);
        ra1 = *(const float4*)(aB + ard[3][1]);
        BARRIER;
        abf = cvt8(ra0, ra1);
        __builtin_amdgcn_s_setprio(1);
        #pragma unroll
        for (int g = 0; g < 8; ++g)
            acc[3][g] = __builtin_amdgcn_mfma_f32_16x16x32_bf16(
                abf, bfr[g], acc[3][g], 0, 0, 0);
        __builtin_amdgcn_s_setprio(0);
        // boundary: wait A(kt+1),B(kt+1) (leave A(kt+2) in flight)
        asm volatile("s_waitcnt vmcnt(2)" ::: "memory");
        BARRIER;
    }
    #undef STAGE_A
    #undef STAGE_B

    // ---- fused epilogue: pf store + u partials ----
    const int bidx = Mbase >> 12;
    const float* pqb = pq + (bidx << 9);
    float vv[8], pv[8];
    #pragma unroll
    for (int g = 0; g < 8; ++g) {
        const int c = wn * 128 + g * 16 + fm;
        vv[g] = v[c];
        pv[g] = pqb[c];
    }
    #pragma unroll
    for (int f = 0; f < 4; ++f) {
        #pragma unroll
        for (int rr = 0; rr < 4; ++rr) {
            const int rloc = wm * 64 + f * 16 + fkg * 4 + rr;
            float* prow = pf + (size_t)(Mbase + rloc) * HDIM + wn * 128 + fm;
            float s = 0.0f;
            #pragma unroll
            for (int g = 0; g < 8; ++g) {
                const float val = acc[f][g][rr];
                __builtin_nontemporal_store(val, &prow[g * 16]);
                s += vv[g] * fast_tanh(val + pv[g]);
            }
            s += __shfl_xor(s, 1);
            s += __shfl_xor(s, 2);
            s += __shfl_xor(s, 4);
            s += __shfl_xor(s, 8);
            if (fm == 0) uls[rloc * 4 + wn] = s;
        }
    }
    __syncthreads();
    if (t < 128) {
        const float4 p4 = *(const float4*)(uls + t * 4);
        const float u = p4.x + p4.y + p4.z + p4.w;
        logits[Mbase + t] = 10.0f * fast_tanh(u);
    }
}

extern "C" void kernel_launch(void* const* d_in, const int* in_sizes, int n_in,
                              void* d_out, int out_size, void* d_ws, size_t ws_size,
                              hipStream_t stream) {
    const float* features = (const float*)d_in[0];
    const float* query    = (const float*)d_in[1];
    const float* Wf       = (const float*)d_in[2];
    const float* Wq       = (const float*)d_in[3];
    const float* v        = (const float*)d_in[4];

    float* pf     = (float*)d_out;
    float* logits = (float*)d_out + 33554432;

    float* ws_pq  = (float*)d_ws;                    // 8192 f32  (32KB)
    short* ws_bsh = (short*)(ws_pq + 8192);          // 524288 bf16 (1MB)

    bshuf_kernel<<<256, 256, 0, stream>>>(Wf, ws_bsh);
    pq_kernel<<<16, 512, 0, stream>>>(query, Wq, ws_pq);
    gemm_kernel<<<512, 512, 0, stream>>>(features, ws_bsh, ws_pq, v, pf, logits);
}